// Round 8
// baseline (127.879 us; speedup 1.0000x reference)
//
#include <hip/hip_runtime.h>

#define NV    150000
#define CIN   32
#define COUT  64
#define EPSF  1e-5f
#define NCOPY 16

#define NTHR   256
#define NTILES (NV / 16)              // 9375 exact
#define NBLK1  ((NTILES + 3) / 4)     // 2344 blocks, 1 tile per wave

#define NBLK2  2344
#define TOTAL4 ((long)NV * COUT / 4)  // 2,400,000 float4 chunks
#define STRIDE2 ((long)NBLK2 * NTHR)  // 600,064

typedef short  bf16x8 __attribute__((ext_vector_type(8)));
typedef float  f32x4  __attribute__((ext_vector_type(4)));

__device__ __forceinline__ short f2bf(float x) {
    union { float f; unsigned u; } c; c.f = x;
    return (short)((c.u + 0x7FFFu + ((c.u >> 16) & 1u)) >> 16);
}

// ---------------------------------------------------------------------------
// K1: one wave per 16-voxel tile. Scan loads issue first (overlap center
// MFMA); center tap via MFMA (W13 from L2); off-center taps drained TWO
// active k's per iteration (independent gather chains). Fused BN partials.
// ---------------------------------------------------------------------------
__global__ __launch_bounds__(NTHR) void k_conv(
    const float* __restrict__ feat,    // [NV, CIN]
    const float* __restrict__ weight,  // [27, CIN, COUT]
    const int*   __restrict__ nbr,     // [27, NV]
    float*       __restrict__ out,     // [NV, COUT]
    float*       __restrict__ gstats)  // [NCOPY][128]
{
    const int tid  = threadIdx.x;
    const int lane = tid & 63;
    const int quad = lane >> 4;
    const int lm   = lane & 15;
    const int wid  = blockIdx.x * 4 + (tid >> 6);   // == tile id

    f32x4 ssum = {0.f, 0.f, 0.f, 0.f};
    f32x4 qsum = {0.f, 0.f, 0.f, 0.f};
    f32x4 acc[4] = {{0.f,0.f,0.f,0.f},{0.f,0.f,0.f,0.f},{0.f,0.f,0.f,0.f},{0.f,0.f,0.f,0.f}};

    const bool have_tile = (wid < NTILES);
    const int v0 = have_tile ? wid * 16 : 0;

    if (have_tile) {
        // ---- 1) scan loads first: 26 taps x 16 voxels = 416 items ----
        int sidx[7];
#pragma unroll
        for (int it = 0; it < 7; ++it) {
            const int item = lane + it * 64;
            int idx = -1;
            if (item < 416) {
                const int kp = item >> 4;
                const int k  = kp + (kp >= 13);
                idx = nbr[(long)k * NV + v0 + (item & 15)];
            }
            sidx[it] = idx;
        }

        // ---- 2) center tap MFMA (independent of scan loads) ----
        {
            const float4* fp = (const float4*)(feat + (long)(v0 + lm) * CIN + quad * 8);
            const float4 fa = fp[0];
            const float4 fb = fp[1];
            bf16x8 afr;
            afr[0] = f2bf(fa.x); afr[1] = f2bf(fa.y); afr[2] = f2bf(fa.z); afr[3] = f2bf(fa.w);
            afr[4] = f2bf(fb.x); afr[5] = f2bf(fb.y); afr[6] = f2bf(fb.z); afr[7] = f2bf(fb.w);
#pragma unroll
            for (int b = 0; b < 4; ++b) {
                const float* wsrc = weight + 13 * CIN * COUT + (quad * 8) * COUT + b * 16 + lm;
                bf16x8 bfr;
#pragma unroll
                for (int j = 0; j < 8; ++j) bfr[j] = f2bf(wsrc[j * COUT]);
                acc[b] = __builtin_amdgcn_mfma_f32_16x16x32_bf16(afr, bfr, acc[b], 0, 0, 0);
            }
        }

        // ---- 3) ballots -> wave-uniform 26-bit active-k mask ----
        unsigned int kmask = 0u;
#pragma unroll
        for (int it = 0; it < 7; ++it) {
            const unsigned long long m = __ballot(sidx[it] >= 0);
            kmask |= ((m & 0xFFFFull)         ? 1u : 0u) << (it * 4 + 0);
            kmask |= (((m >> 16) & 0xFFFFull) ? 1u : 0u) << (it * 4 + 1);
            kmask |= (((m >> 32) & 0xFFFFull) ? 1u : 0u) << (it * 4 + 2);
            kmask |= ((m >> 48)               ? 1u : 0u) << (it * 4 + 3);
        }

        // ---- 4) drain: 2 active k's per iteration, independent chains ----
        while (kmask) {
            const int kpA = __ffs(kmask) - 1;
            kmask &= kmask - 1u;
            int kpB = -1;
            if (kmask) { kpB = __ffs(kmask) - 1; kmask &= kmask - 1u; }
            const int kA = kpA + (kpA >= 13);
            const int kB = (kpB >= 0) ? (kpB + (kpB >= 13)) : kA;  // kA reused: A-frag zeroed

            const int idxA = nbr[(long)kA * NV + v0 + lm];
            const int idxB = (kpB >= 0) ? nbr[(long)kB * NV + v0 + lm] : -1;

            const float4* fpA = (const float4*)(feat + (long)(idxA < 0 ? 0 : idxA) * CIN + quad * 8);
            const float4* fpB = (const float4*)(feat + (long)(idxB < 0 ? 0 : idxB) * CIN + quad * 8);
            float4 gaA = fpA[0], gbA = fpA[1];
            float4 gaB = fpB[0], gbB = fpB[1];
            if (idxA < 0) { gaA = make_float4(0.f,0.f,0.f,0.f); gbA = make_float4(0.f,0.f,0.f,0.f); }
            if (idxB < 0) { gaB = make_float4(0.f,0.f,0.f,0.f); gbB = make_float4(0.f,0.f,0.f,0.f); }

            bf16x8 naA, naB;
            naA[0] = f2bf(gaA.x); naA[1] = f2bf(gaA.y); naA[2] = f2bf(gaA.z); naA[3] = f2bf(gaA.w);
            naA[4] = f2bf(gbA.x); naA[5] = f2bf(gbA.y); naA[6] = f2bf(gbA.z); naA[7] = f2bf(gbA.w);
            naB[0] = f2bf(gaB.x); naB[1] = f2bf(gaB.y); naB[2] = f2bf(gaB.z); naB[3] = f2bf(gaB.w);
            naB[4] = f2bf(gbB.x); naB[5] = f2bf(gbB.y); naB[6] = f2bf(gbB.z); naB[7] = f2bf(gbB.w);

            const float* wkA = weight + (long)kA * CIN * COUT + (quad * 8) * COUT + lm;
            const float* wkB = weight + (long)kB * CIN * COUT + (quad * 8) * COUT + lm;
#pragma unroll
            for (int b = 0; b < 4; ++b) {
                bf16x8 wbA, wbB;
#pragma unroll
                for (int j = 0; j < 8; ++j) {
                    wbA[j] = f2bf(wkA[j * COUT + b * 16]);
                    wbB[j] = f2bf(wkB[j * COUT + b * 16]);
                }
                acc[b] = __builtin_amdgcn_mfma_f32_16x16x32_bf16(naA, wbA, acc[b], 0, 0, 0);
                acc[b] = __builtin_amdgcn_mfma_f32_16x16x32_bf16(naB, wbB, acc[b], 0, 0, 0);
            }
        }

        // ---- 5) store rows + BN partials from final values ----
#pragma unroll
        for (int b = 0; b < 4; ++b) {
            const float r0 = acc[b][0], r1 = acc[b][1], r2 = acc[b][2], r3 = acc[b][3];
            out[(long)(v0 + quad * 4 + 0) * COUT + b * 16 + lm] = r0;
            out[(long)(v0 + quad * 4 + 1) * COUT + b * 16 + lm] = r1;
            out[(long)(v0 + quad * 4 + 2) * COUT + b * 16 + lm] = r2;
            out[(long)(v0 + quad * 4 + 3) * COUT + b * 16 + lm] = r3;
            ssum[b] += r0 + r1 + r2 + r3;
            qsum[b] += r0 * r0 + r1 * r1 + r2 * r2 + r3 * r3;
        }
    }

    // ---- butterfly over quads (channel b*16+lm identical across quads) ----
#pragma unroll
    for (int off = 16; off < 64; off <<= 1) {
#pragma unroll
        for (int b = 0; b < 4; ++b) {
            ssum[b] += __shfl_xor(ssum[b], off);
            qsum[b] += __shfl_xor(qsum[b], off);
        }
    }

    __shared__ float ls[4][128];
    const int wv = tid >> 6;
    if (quad == 0) {
#pragma unroll
        for (int b = 0; b < 4; ++b) {
            ls[wv][b * 16 + lm]      = ssum[b];
            ls[wv][64 + b * 16 + lm] = qsum[b];
        }
    }
    __syncthreads();
    if (tid < 128) {
        const float v = ls[0][tid] + ls[1][tid] + ls[2][tid] + ls[3][tid];
        atomicAdd(gstats + (blockIdx.x & (NCOPY - 1)) * 128 + tid, v);
    }
}

// ---------------------------------------------------------------------------
// K2: redundant stripe reduce -> scale/shift, then in-place affine + ReLU.
// Exact cover: 2344 blocks x 256 thr x 4 chunks = 2,400,256 >= 2,400,000.
// Chunks 0..2 unconditional, chunk 3 bounds-checked. 4 independent loads.
// ---------------------------------------------------------------------------
__global__ __launch_bounds__(NTHR) void k_norm(
    float*       __restrict__ out,
    const float* __restrict__ gstats,
    const float* __restrict__ gamma,
    const float* __restrict__ beta)
{
    __shared__ float sscale[COUT];
    __shared__ float sshift[COUT];
    const int tid = threadIdx.x;
    if (tid < COUT) {
        float s = 0.f, q = 0.f;
#pragma unroll
        for (int cp = 0; cp < NCOPY; ++cp) {
            s += gstats[cp * 128 + tid];
            q += gstats[cp * 128 + 64 + tid];
        }
        const float inv_n = 1.f / (float)NV;
        const float mean = s * inv_n;
        float var = q * inv_n - mean * mean;
        var = fmaxf(var, 0.f);
        const float rstd = rsqrtf(var + EPSF);
        const float sc = gamma[tid] * rstd;
        sscale[tid] = sc;
        sshift[tid] = beta[tid] - mean * sc;
    }
    __syncthreads();

    const int g4 = (tid & 15) * 4;
    const float4 SC = make_float4(sscale[g4], sscale[g4 + 1], sscale[g4 + 2], sscale[g4 + 3]);
    const float4 SH = make_float4(sshift[g4], sshift[g4 + 1], sshift[g4 + 2], sshift[g4 + 3]);

    float4* o4 = (float4*)out;
    const long base = (long)blockIdx.x * NTHR + tid;

    float4 v0 = o4[base];
    float4 v1 = o4[base + STRIDE2];
    float4 v2 = o4[base + 2 * STRIDE2];
    const long i3 = base + 3 * STRIDE2;
    const bool has3 = (i3 < TOTAL4);
    float4 v3 = has3 ? o4[i3] : make_float4(0.f, 0.f, 0.f, 0.f);

    v0.x = fmaxf(v0.x * SC.x + SH.x, 0.f); v0.y = fmaxf(v0.y * SC.y + SH.y, 0.f);
    v0.z = fmaxf(v0.z * SC.z + SH.z, 0.f); v0.w = fmaxf(v0.w * SC.w + SH.w, 0.f);
    v1.x = fmaxf(v1.x * SC.x + SH.x, 0.f); v1.y = fmaxf(v1.y * SC.y + SH.y, 0.f);
    v1.z = fmaxf(v1.z * SC.z + SH.z, 0.f); v1.w = fmaxf(v1.w * SC.w + SH.w, 0.f);
    v2.x = fmaxf(v2.x * SC.x + SH.x, 0.f); v2.y = fmaxf(v2.y * SC.y + SH.y, 0.f);
    v2.z = fmaxf(v2.z * SC.z + SH.z, 0.f); v2.w = fmaxf(v2.w * SC.w + SH.w, 0.f);
    v3.x = fmaxf(v3.x * SC.x + SH.x, 0.f); v3.y = fmaxf(v3.y * SC.y + SH.y, 0.f);
    v3.z = fmaxf(v3.z * SC.z + SH.z, 0.f); v3.w = fmaxf(v3.w * SC.w + SH.w, 0.f);

    o4[base] = v0;
    o4[base + STRIDE2] = v1;
    o4[base + 2 * STRIDE2] = v2;
    if (has3) o4[i3] = v3;
}

// ---------------------------------------------------------------------------
extern "C" void kernel_launch(void* const* d_in, const int* in_sizes, int n_in,
                              void* d_out, int out_size, void* d_ws, size_t ws_size,
                              hipStream_t stream) {
    const float* feat   = (const float*)d_in[0];
    const float* weight = (const float*)d_in[1];
    const float* gamma  = (const float*)d_in[2];
    const float* beta   = (const float*)d_in[3];
    const int*   nbr    = (const int*)d_in[4];
    float* out = (float*)d_out;

    float* gstats = (float*)d_ws;   // NCOPY * 128 floats = 8 KB

    hipMemsetAsync(d_ws, 0, NCOPY * 128 * sizeof(float), stream);

    k_conv<<<NBLK1, NTHR, 0, stream>>>(feat, weight, nbr, out, gstats);
    k_norm<<<NBLK2, NTHR, 0, stream>>>(out, gstats, gamma, beta);
}

// Round 9
// 120.610 us; speedup vs baseline: 1.0603x; 1.0603x over previous
//
#include <hip/hip_runtime.h>

#define NV    150000
#define CIN   32
#define COUT  64
#define EPSF  1e-5f
#define NCOPY 16

#define NTHR   256
#define NTILES (NV / 16)              // 9375 exact
#define NBLK1  ((NTILES + 3) / 4)     // 2344 blocks, 1 tile per wave

#define NBLK2  2344
#define TOTAL4 ((long)NV * COUT / 4)  // 2,400,000 float4 chunks
#define STRIDE2 ((long)NBLK2 * NTHR)  // 600,064

// prep grid: feat blocks + 27 weight blocks + 1 gstats block
#define FEAT_T   (NV * CIN / 8)       // 600,000 threads, 8 floats each
#define FEATBLK  ((FEAT_T + NTHR - 1) / NTHR)   // 2344
#define PREPBLK  (FEATBLK + 27 + 1)             // 2372

// ws layout (bytes):
//   [0, 9600000)            ushort feat_bf[NV*CIN]
//   [9600000, 9710592)      ushort wfrag[27*4*64*8]  (B-fragment swizzled)
//   [9710592, 9718784)      float  gstats[NCOPY*128]
#define WS_WFRAG  9600000
#define WS_GSTATS 9710592

typedef short  bf16x8 __attribute__((ext_vector_type(8)));
typedef float  f32x4  __attribute__((ext_vector_type(4)));

union u4bf { uint4 u; bf16x8 h; };

__device__ __forceinline__ unsigned pack_bf2(float a, float b) {
    union { float f; unsigned u; } ca, cb;
    ca.f = a; cb.f = b;
    const unsigned lo = (ca.u + 0x7FFFu + ((ca.u >> 16) & 1u)) >> 16;
    const unsigned hi = (cb.u + 0x7FFFu + ((cb.u >> 16) & 1u)) & 0xFFFF0000u;
    return lo | hi;
}

// ---------------------------------------------------------------------------
// K0: prep — feat->bf16, weights->B-fragment-swizzled bf16, zero gstats.
// ---------------------------------------------------------------------------
__global__ __launch_bounds__(NTHR) void k_prep(
    const float* __restrict__ feat,
    const float* __restrict__ weight,
    char*        __restrict__ ws)
{
    const int b = blockIdx.x;
    if (b < FEATBLK) {
        const int t = b * NTHR + threadIdx.x;
        if (t < FEAT_T) {
            const float4* src = (const float4*)(feat) + t * 2;
            const float4 f0 = src[0];
            const float4 f1 = src[1];
            uint4 o;
            o.x = pack_bf2(f0.x, f0.y);
            o.y = pack_bf2(f0.z, f0.w);
            o.z = pack_bf2(f1.x, f1.y);
            o.w = pack_bf2(f1.z, f1.w);
            ((uint4*)ws)[t] = o;
        }
    } else if (b < FEATBLK + 27) {
        const int k    = b - FEATBLK;
        const int bb   = threadIdx.x >> 6;       // cout block 0..3
        const int lane = threadIdx.x & 63;
        const int quad = lane >> 4;
        const int lm   = lane & 15;
        // entry holds weight[k][quad*8+j][bb*16+lm], j=0..7
        const float* wsrc = weight + (long)k * CIN * COUT + (quad * 8) * COUT + bb * 16 + lm;
        float f[8];
#pragma unroll
        for (int j = 0; j < 8; ++j) f[j] = wsrc[j * COUT];
        uint4 o;
        o.x = pack_bf2(f[0], f[1]);
        o.y = pack_bf2(f[2], f[3]);
        o.z = pack_bf2(f[4], f[5]);
        o.w = pack_bf2(f[6], f[7]);
        ((uint4*)(ws + WS_WFRAG))[(k * 4 + bb) * 64 + lane] = o;
    } else {
        float* gs = (float*)(ws + WS_GSTATS);
#pragma unroll
        for (int i = 0; i < 8; ++i) gs[threadIdx.x + i * NTHR] = 0.f;
    }
}

// ---------------------------------------------------------------------------
// K1: one wave per 16-voxel tile. All operands pre-converted bf16; drain
// indices come from scan registers via shfl (no reload). Fused BN partials.
// ---------------------------------------------------------------------------
__global__ __launch_bounds__(NTHR) void k_conv(
    const char*  __restrict__ ws_ro,   // feat_bf + wfrag
    const int*   __restrict__ nbr,     // [27, NV]
    float*       __restrict__ out,     // [NV, COUT]
    float*       __restrict__ gstats)  // [NCOPY][128]
{
    const uint4* fb = (const uint4*)ws_ro;                 // feat_bf rows: 4 uint4/row
    const uint4* wf = (const uint4*)(ws_ro + WS_WFRAG);    // wfrag[(k*4+b)*64+lane]

    const int tid  = threadIdx.x;
    const int lane = tid & 63;
    const int quad = lane >> 4;
    const int lm   = lane & 15;
    const int wid  = blockIdx.x * 4 + (tid >> 6);   // == tile id

    f32x4 ssum = {0.f, 0.f, 0.f, 0.f};
    f32x4 qsum = {0.f, 0.f, 0.f, 0.f};
    f32x4 acc[4] = {{0.f,0.f,0.f,0.f},{0.f,0.f,0.f,0.f},{0.f,0.f,0.f,0.f},{0.f,0.f,0.f,0.f}};

    const bool have_tile = (wid < NTILES);
    const int v0 = have_tile ? wid * 16 : 0;

    if (have_tile) {
        // ---- 1) scan loads: 26 taps x 16 voxels = 416 items ----
        int sidx[7];
#pragma unroll
        for (int it = 0; it < 7; ++it) {
            const int item = lane + it * 64;
            int idx = -1;
            if (item < 416) {
                const int kp = item >> 4;
                const int k  = kp + (kp >= 13);
                idx = nbr[(long)k * NV + v0 + (item & 15)];
            }
            sidx[it] = idx;
        }

        // ---- 2) center tap MFMA ----
        {
            u4bf a; a.u = fb[(v0 + lm) * 4 + quad];
#pragma unroll
            for (int b = 0; b < 4; ++b) {
                u4bf w; w.u = wf[(13 * 4 + b) * 64 + lane];
                acc[b] = __builtin_amdgcn_mfma_f32_16x16x32_bf16(a.h, w.h, acc[b], 0, 0, 0);
            }
        }

        // ---- 3) ballots -> wave-uniform 26-bit active-k mask ----
        unsigned int kmask = 0u;
#pragma unroll
        for (int it = 0; it < 7; ++it) {
            const unsigned long long m = __ballot(sidx[it] >= 0);
            kmask |= ((m & 0xFFFFull)         ? 1u : 0u) << (it * 4 + 0);
            kmask |= (((m >> 16) & 0xFFFFull) ? 1u : 0u) << (it * 4 + 1);
            kmask |= (((m >> 32) & 0xFFFFull) ? 1u : 0u) << (it * 4 + 2);
            kmask |= ((m >> 48)               ? 1u : 0u) << (it * 4 + 3);
        }

        // ---- 4) drain: 2 active k's per iteration ----
        while (kmask) {
            const int kpA = __ffs(kmask) - 1;
            kmask &= kmask - 1u;
            int kpB = -1;
            if (kmask) { kpB = __ffs(kmask) - 1; kmask &= kmask - 1u; }
            const int kA = kpA + (kpA >= 13);
            const int kB = (kpB >= 0) ? (kpB + (kpB >= 13)) : kA;

            // indices from scan registers (kp>>2 is wave-uniform)
            int rawA, rawB;
            switch (kpA >> 2) {
                case 0: rawA = sidx[0]; break; case 1: rawA = sidx[1]; break;
                case 2: rawA = sidx[2]; break; case 3: rawA = sidx[3]; break;
                case 4: rawA = sidx[4]; break; case 5: rawA = sidx[5]; break;
                default: rawA = sidx[6]; break;
            }
            const int kpB2 = (kpB >= 0) ? kpB : kpA;
            switch (kpB2 >> 2) {
                case 0: rawB = sidx[0]; break; case 1: rawB = sidx[1]; break;
                case 2: rawB = sidx[2]; break; case 3: rawB = sidx[3]; break;
                case 4: rawB = sidx[4]; break; case 5: rawB = sidx[5]; break;
                default: rawB = sidx[6]; break;
            }
            const int idxA = __shfl(rawA, ((kpA & 3) << 4) | lm);
            int idxB = __shfl(rawB, ((kpB2 & 3) << 4) | lm);
            if (kpB < 0) idxB = -1;

            u4bf aA, aB;
            aA.u = fb[(long)(idxA < 0 ? 0 : idxA) * 4 + quad];
            aB.u = fb[(long)(idxB < 0 ? 0 : idxB) * 4 + quad];
            if (idxA < 0) aA.u = make_uint4(0u, 0u, 0u, 0u);
            if (idxB < 0) aB.u = make_uint4(0u, 0u, 0u, 0u);

#pragma unroll
            for (int b = 0; b < 4; ++b) {
                u4bf wA, wB;
                wA.u = wf[(kA * 4 + b) * 64 + lane];
                wB.u = wf[(kB * 4 + b) * 64 + lane];
                acc[b] = __builtin_amdgcn_mfma_f32_16x16x32_bf16(aA.h, wA.h, acc[b], 0, 0, 0);
                acc[b] = __builtin_amdgcn_mfma_f32_16x16x32_bf16(aB.h, wB.h, acc[b], 0, 0, 0);
            }
        }

        // ---- 5) store rows + BN partials ----
#pragma unroll
        for (int b = 0; b < 4; ++b) {
            const float r0 = acc[b][0], r1 = acc[b][1], r2 = acc[b][2], r3 = acc[b][3];
            out[(long)(v0 + quad * 4 + 0) * COUT + b * 16 + lm] = r0;
            out[(long)(v0 + quad * 4 + 1) * COUT + b * 16 + lm] = r1;
            out[(long)(v0 + quad * 4 + 2) * COUT + b * 16 + lm] = r2;
            out[(long)(v0 + quad * 4 + 3) * COUT + b * 16 + lm] = r3;
            ssum[b] += r0 + r1 + r2 + r3;
            qsum[b] += r0 * r0 + r1 * r1 + r2 * r2 + r3 * r3;
        }
    }

    // ---- butterfly over quads ----
#pragma unroll
    for (int off = 16; off < 64; off <<= 1) {
#pragma unroll
        for (int b = 0; b < 4; ++b) {
            ssum[b] += __shfl_xor(ssum[b], off);
            qsum[b] += __shfl_xor(qsum[b], off);
        }
    }

    __shared__ float ls[4][128];
    const int wv = tid >> 6;
    if (quad == 0) {
#pragma unroll
        for (int b = 0; b < 4; ++b) {
            ls[wv][b * 16 + lm]      = ssum[b];
            ls[wv][64 + b * 16 + lm] = qsum[b];
        }
    }
    __syncthreads();
    if (tid < 128) {
        const float v = ls[0][tid] + ls[1][tid] + ls[2][tid] + ls[3][tid];
        atomicAdd(gstats + (blockIdx.x & (NCOPY - 1)) * 128 + tid, v);
    }
}

// ---------------------------------------------------------------------------
// K2: redundant stripe reduce -> scale/shift, then in-place affine + ReLU.
// ---------------------------------------------------------------------------
__global__ __launch_bounds__(NTHR) void k_norm(
    float*       __restrict__ out,
    const float* __restrict__ gstats,
    const float* __restrict__ gamma,
    const float* __restrict__ beta)
{
    __shared__ float sscale[COUT];
    __shared__ float sshift[COUT];
    const int tid = threadIdx.x;
    if (tid < COUT) {
        float s = 0.f, q = 0.f;
#pragma unroll
        for (int cp = 0; cp < NCOPY; ++cp) {
            s += gstats[cp * 128 + tid];
            q += gstats[cp * 128 + 64 + tid];
        }
        const float inv_n = 1.f / (float)NV;
        const float mean = s * inv_n;
        float var = q * inv_n - mean * mean;
        var = fmaxf(var, 0.f);
        const float rstd = rsqrtf(var + EPSF);
        const float sc = gamma[tid] * rstd;
        sscale[tid] = sc;
        sshift[tid] = beta[tid] - mean * sc;
    }
    __syncthreads();

    const int g4 = (tid & 15) * 4;
    const float4 SC = make_float4(sscale[g4], sscale[g4 + 1], sscale[g4 + 2], sscale[g4 + 3]);
    const float4 SH = make_float4(sshift[g4], sshift[g4 + 1], sshift[g4 + 2], sshift[g4 + 3]);

    float4* o4 = (float4*)out;
    const long base = (long)blockIdx.x * NTHR + tid;

    float4 v0 = o4[base];
    float4 v1 = o4[base + STRIDE2];
    float4 v2 = o4[base + 2 * STRIDE2];
    const long i3 = base + 3 * STRIDE2;
    const bool has3 = (i3 < TOTAL4);
    float4 v3 = has3 ? o4[i3] : make_float4(0.f, 0.f, 0.f, 0.f);

    v0.x = fmaxf(v0.x * SC.x + SH.x, 0.f); v0.y = fmaxf(v0.y * SC.y + SH.y, 0.f);
    v0.z = fmaxf(v0.z * SC.z + SH.z, 0.f); v0.w = fmaxf(v0.w * SC.w + SH.w, 0.f);
    v1.x = fmaxf(v1.x * SC.x + SH.x, 0.f); v1.y = fmaxf(v1.y * SC.y + SH.y, 0.f);
    v1.z = fmaxf(v1.z * SC.z + SH.z, 0.f); v1.w = fmaxf(v1.w * SC.w + SH.w, 0.f);
    v2.x = fmaxf(v2.x * SC.x + SH.x, 0.f); v2.y = fmaxf(v2.y * SC.y + SH.y, 0.f);
    v2.z = fmaxf(v2.z * SC.z + SH.z, 0.f); v2.w = fmaxf(v2.w * SC.w + SH.w, 0.f);
    v3.x = fmaxf(v3.x * SC.x + SH.x, 0.f); v3.y = fmaxf(v3.y * SC.y + SH.y, 0.f);
    v3.z = fmaxf(v3.z * SC.z + SH.z, 0.f); v3.w = fmaxf(v3.w * SC.w + SH.w, 0.f);

    o4[base] = v0;
    o4[base + STRIDE2] = v1;
    o4[base + 2 * STRIDE2] = v2;
    if (has3) o4[i3] = v3;
}

// ---------------------------------------------------------------------------
extern "C" void kernel_launch(void* const* d_in, const int* in_sizes, int n_in,
                              void* d_out, int out_size, void* d_ws, size_t ws_size,
                              hipStream_t stream) {
    const float* feat   = (const float*)d_in[0];
    const float* weight = (const float*)d_in[1];
    const float* gamma  = (const float*)d_in[2];
    const float* beta   = (const float*)d_in[3];
    const int*   nbr    = (const int*)d_in[4];
    float* out = (float*)d_out;

    char*  ws     = (char*)d_ws;
    float* gstats = (float*)(ws + WS_GSTATS);

    k_prep<<<PREPBLK, NTHR, 0, stream>>>(feat, weight, ws);
    k_conv<<<NBLK1, NTHR, 0, stream>>>(ws, nbr, out, gstats);
    k_norm<<<NBLK2, NTHR, 0, stream>>>(out, gstats, gamma, beta);
}

// Round 10
// 116.132 us; speedup vs baseline: 1.1012x; 1.0386x over previous
//
#include <hip/hip_runtime.h>

#define NV    150000
#define CIN   32
#define COUT  64
#define EPSF  1e-5f
#define NCOPY 16

#define NTHR   256
#define NTILES (NV / 16)              // 9375 exact
#define NBLK1  ((NTILES + 3) / 4)     // 2344 blocks, 1 tile per wave

// k_norm: chunks of 8 channels (one uint4 of bf16)
#define CH8    (NV * COUT / 8)        // 1,200,000
#define NBLK2  1172
#define STRIDE2 (NBLK2 * NTHR)        // 300,032 (divisible by 8)

// prep grid: feat blocks + 27 weight blocks + 1 gstats block
#define FEAT_T   (NV * CIN / 8)       // 600,000 threads, 8 floats each
#define FEATBLK  ((FEAT_T + NTHR - 1) / NTHR)   // 2344
#define PREPBLK  (FEATBLK + 27 + 1)             // 2372

// ws layout (bytes):
//   [0, 9600000)            ushort feat_bf[NV*CIN]
//   [9600000, 9710592)      ushort wfrag[27*4*64*8]  (B-fragment swizzled)
//   [9710592, 9718784)      float  gstats[NCOPY*128]
//   [9720832, 28920832)     ushort out_bf[NV*COUT]   (conv result, bf16)
#define WS_WFRAG  9600000
#define WS_GSTATS 9710592
#define WS_OUTBF  9720832

typedef short  bf16x8 __attribute__((ext_vector_type(8)));
typedef float  f32x4  __attribute__((ext_vector_type(4)));

union u4bf { uint4 u; bf16x8 h; };

__device__ __forceinline__ unsigned pack_bf2(float a, float b) {
    union { float f; unsigned u; } ca, cb;
    ca.f = a; cb.f = b;
    const unsigned lo = (ca.u + 0x7FFFu + ((ca.u >> 16) & 1u)) >> 16;
    const unsigned hi = (cb.u + 0x7FFFu + ((cb.u >> 16) & 1u)) & 0xFFFF0000u;
    return lo | hi;
}

__device__ __forceinline__ unsigned short bf16r(float a) {
    union { float f; unsigned u; } c; c.f = a;
    return (unsigned short)((c.u + 0x7FFFu + ((c.u >> 16) & 1u)) >> 16);
}

// ---------------------------------------------------------------------------
// K0: prep — feat->bf16, weights->B-fragment-swizzled bf16, zero gstats.
// ---------------------------------------------------------------------------
__global__ __launch_bounds__(NTHR) void k_prep(
    const float* __restrict__ feat,
    const float* __restrict__ weight,
    char*        __restrict__ ws)
{
    const int b = blockIdx.x;
    if (b < FEATBLK) {
        const int t = b * NTHR + threadIdx.x;
        if (t < FEAT_T) {
            const float4* src = (const float4*)(feat) + t * 2;
            const float4 f0 = src[0];
            const float4 f1 = src[1];
            uint4 o;
            o.x = pack_bf2(f0.x, f0.y);
            o.y = pack_bf2(f0.z, f0.w);
            o.z = pack_bf2(f1.x, f1.y);
            o.w = pack_bf2(f1.z, f1.w);
            ((uint4*)ws)[t] = o;
        }
    } else if (b < FEATBLK + 27) {
        const int k    = b - FEATBLK;
        const int bb   = threadIdx.x >> 6;       // cout block 0..3
        const int lane = threadIdx.x & 63;
        const int quad = lane >> 4;
        const int lm   = lane & 15;
        const float* wsrc = weight + (long)k * CIN * COUT + (quad * 8) * COUT + bb * 16 + lm;
        float f[8];
#pragma unroll
        for (int j = 0; j < 8; ++j) f[j] = wsrc[j * COUT];
        uint4 o;
        o.x = pack_bf2(f[0], f[1]);
        o.y = pack_bf2(f[2], f[3]);
        o.z = pack_bf2(f[4], f[5]);
        o.w = pack_bf2(f[6], f[7]);
        ((uint4*)(ws + WS_WFRAG))[(k * 4 + bb) * 64 + lane] = o;
    } else {
        float* gs = (float*)(ws + WS_GSTATS);
#pragma unroll
        for (int i = 0; i < 8; ++i) gs[threadIdx.x + i * NTHR] = 0.f;
    }
}

// ---------------------------------------------------------------------------
// K1: one wave per 16-voxel tile. All operands pre-converted bf16; drain
// indices from scan registers via shfl. Writes conv result as bf16 to ws.
// BN partials computed from f32 accumulators -> striped atomics.
// ---------------------------------------------------------------------------
__global__ __launch_bounds__(NTHR) void k_conv(
    char*        __restrict__ ws,      // feat_bf + wfrag + gstats + out_bf
    const int*   __restrict__ nbr,     // [27, NV]
    float*       __restrict__ gstats)
{
    const uint4* fb = (const uint4*)ws;                 // feat_bf rows: 4 uint4/row
    const uint4* wf = (const uint4*)(ws + WS_WFRAG);    // wfrag[(k*4+b)*64+lane]
    unsigned short* ob = (unsigned short*)(ws + WS_OUTBF);

    const int tid  = threadIdx.x;
    const int lane = tid & 63;
    const int quad = lane >> 4;
    const int lm   = lane & 15;
    const int wid  = blockIdx.x * 4 + (tid >> 6);   // == tile id

    f32x4 ssum = {0.f, 0.f, 0.f, 0.f};
    f32x4 qsum = {0.f, 0.f, 0.f, 0.f};
    f32x4 acc[4] = {{0.f,0.f,0.f,0.f},{0.f,0.f,0.f,0.f},{0.f,0.f,0.f,0.f},{0.f,0.f,0.f,0.f}};

    const bool have_tile = (wid < NTILES);
    const int v0 = have_tile ? wid * 16 : 0;

    if (have_tile) {
        // ---- 1) scan loads: 26 taps x 16 voxels = 416 items ----
        int sidx[7];
#pragma unroll
        for (int it = 0; it < 7; ++it) {
            const int item = lane + it * 64;
            int idx = -1;
            if (item < 416) {
                const int kp = item >> 4;
                const int k  = kp + (kp >= 13);
                idx = nbr[(long)k * NV + v0 + (item & 15)];
            }
            sidx[it] = idx;
        }

        // ---- 2) center tap MFMA ----
        {
            u4bf a; a.u = fb[(v0 + lm) * 4 + quad];
#pragma unroll
            for (int b = 0; b < 4; ++b) {
                u4bf w; w.u = wf[(13 * 4 + b) * 64 + lane];
                acc[b] = __builtin_amdgcn_mfma_f32_16x16x32_bf16(a.h, w.h, acc[b], 0, 0, 0);
            }
        }

        // ---- 3) ballots -> wave-uniform 26-bit active-k mask ----
        unsigned int kmask = 0u;
#pragma unroll
        for (int it = 0; it < 7; ++it) {
            const unsigned long long m = __ballot(sidx[it] >= 0);
            kmask |= ((m & 0xFFFFull)         ? 1u : 0u) << (it * 4 + 0);
            kmask |= (((m >> 16) & 0xFFFFull) ? 1u : 0u) << (it * 4 + 1);
            kmask |= (((m >> 32) & 0xFFFFull) ? 1u : 0u) << (it * 4 + 2);
            kmask |= ((m >> 48)               ? 1u : 0u) << (it * 4 + 3);
        }

        // ---- 4) drain: 2 active k's per iteration ----
        while (kmask) {
            const int kpA = __ffs(kmask) - 1;
            kmask &= kmask - 1u;
            int kpB = -1;
            if (kmask) { kpB = __ffs(kmask) - 1; kmask &= kmask - 1u; }
            const int kA = kpA + (kpA >= 13);
            const int kB = (kpB >= 0) ? (kpB + (kpB >= 13)) : kA;

            int rawA, rawB;
            switch (kpA >> 2) {
                case 0: rawA = sidx[0]; break; case 1: rawA = sidx[1]; break;
                case 2: rawA = sidx[2]; break; case 3: rawA = sidx[3]; break;
                case 4: rawA = sidx[4]; break; case 5: rawA = sidx[5]; break;
                default: rawA = sidx[6]; break;
            }
            const int kpB2 = (kpB >= 0) ? kpB : kpA;
            switch (kpB2 >> 2) {
                case 0: rawB = sidx[0]; break; case 1: rawB = sidx[1]; break;
                case 2: rawB = sidx[2]; break; case 3: rawB = sidx[3]; break;
                case 4: rawB = sidx[4]; break; case 5: rawB = sidx[5]; break;
                default: rawB = sidx[6]; break;
            }
            const int idxA = __shfl(rawA, ((kpA & 3) << 4) | lm);
            int idxB = __shfl(rawB, ((kpB2 & 3) << 4) | lm);
            if (kpB < 0) idxB = -1;

            u4bf aA, aB;
            aA.u = fb[(long)(idxA < 0 ? 0 : idxA) * 4 + quad];
            aB.u = fb[(long)(idxB < 0 ? 0 : idxB) * 4 + quad];
            if (idxA < 0) aA.u = make_uint4(0u, 0u, 0u, 0u);
            if (idxB < 0) aB.u = make_uint4(0u, 0u, 0u, 0u);

#pragma unroll
            for (int b = 0; b < 4; ++b) {
                u4bf wA, wB;
                wA.u = wf[(kA * 4 + b) * 64 + lane];
                wB.u = wf[(kB * 4 + b) * 64 + lane];
                acc[b] = __builtin_amdgcn_mfma_f32_16x16x32_bf16(aA.h, wA.h, acc[b], 0, 0, 0);
                acc[b] = __builtin_amdgcn_mfma_f32_16x16x32_bf16(aB.h, wB.h, acc[b], 0, 0, 0);
            }
        }

        // ---- 5) store bf16 rows + BN partials from f32 values ----
#pragma unroll
        for (int b = 0; b < 4; ++b) {
            const float r0 = acc[b][0], r1 = acc[b][1], r2 = acc[b][2], r3 = acc[b][3];
            ob[(long)(v0 + quad * 4 + 0) * COUT + b * 16 + lm] = bf16r(r0);
            ob[(long)(v0 + quad * 4 + 1) * COUT + b * 16 + lm] = bf16r(r1);
            ob[(long)(v0 + quad * 4 + 2) * COUT + b * 16 + lm] = bf16r(r2);
            ob[(long)(v0 + quad * 4 + 3) * COUT + b * 16 + lm] = bf16r(r3);
            ssum[b] += r0 + r1 + r2 + r3;
            qsum[b] += r0 * r0 + r1 * r1 + r2 * r2 + r3 * r3;
        }
    }

    // ---- butterfly over quads ----
#pragma unroll
    for (int off = 16; off < 64; off <<= 1) {
#pragma unroll
        for (int b = 0; b < 4; ++b) {
            ssum[b] += __shfl_xor(ssum[b], off);
            qsum[b] += __shfl_xor(qsum[b], off);
        }
    }

    __shared__ float ls[4][128];
    const int wv = tid >> 6;
    if (quad == 0) {
#pragma unroll
        for (int b = 0; b < 4; ++b) {
            ls[wv][b * 16 + lm]      = ssum[b];
            ls[wv][64 + b * 16 + lm] = qsum[b];
        }
    }
    __syncthreads();
    if (tid < 128) {
        const float v = ls[0][tid] + ls[1][tid] + ls[2][tid] + ls[3][tid];
        atomicAdd(gstats + (blockIdx.x & (NCOPY - 1)) * 128 + tid, v);
    }
}

// ---------------------------------------------------------------------------
// K2: stripe reduce -> scale/shift, then read bf16 conv result, apply
// affine + ReLU, write f32 d_out. 8 channels (one uint4) per chunk;
// 1172 blocks x 256 thr x 4 chunks = 1,200,128 >= 1,200,000.
// ---------------------------------------------------------------------------
__global__ __launch_bounds__(NTHR) void k_norm(
    const char*  __restrict__ ws_ro,   // out_bf
    float*       __restrict__ out,
    const float* __restrict__ gstats,
    const float* __restrict__ gamma,
    const float* __restrict__ beta)
{
    __shared__ float sscale[COUT];
    __shared__ float sshift[COUT];
    const int tid = threadIdx.x;
    if (tid < COUT) {
        float s = 0.f, q = 0.f;
#pragma unroll
        for (int cp = 0; cp < NCOPY; ++cp) {
            s += gstats[cp * 128 + tid];
            q += gstats[cp * 128 + 64 + tid];
        }
        const float inv_n = 1.f / (float)NV;
        const float mean = s * inv_n;
        float var = q * inv_n - mean * mean;
        var = fmaxf(var, 0.f);
        const float rstd = rsqrtf(var + EPSF);
        const float sc = gamma[tid] * rstd;
        sscale[tid] = sc;
        sshift[tid] = beta[tid] - mean * sc;
    }
    __syncthreads();

    const int  base = blockIdx.x * NTHR + tid;     // chunk id (8 channels)
    const int  g8   = (base & 7) * 8;              // fixed: STRIDE2 % 8 == 0
    const float4 SC0 = make_float4(sscale[g8],   sscale[g8+1], sscale[g8+2], sscale[g8+3]);
    const float4 SC1 = make_float4(sscale[g8+4], sscale[g8+5], sscale[g8+6], sscale[g8+7]);
    const float4 SH0 = make_float4(sshift[g8],   sshift[g8+1], sshift[g8+2], sshift[g8+3]);
    const float4 SH1 = make_float4(sshift[g8+4], sshift[g8+5], sshift[g8+6], sshift[g8+7]);

    const uint4* ib = (const uint4*)(ws_ro + WS_OUTBF);
    float4* o4 = (float4*)out;

#pragma unroll
    for (int n = 0; n < 4; ++n) {
        const int c = base + n * STRIDE2;
        if (n == 3 && c >= CH8) break;
        const uint4 u = ib[c];
        union { unsigned u; float f; } t;
        float4 v0, v1;
        t.u = u.x << 16;          v0.x = t.f;
        t.u = u.x & 0xFFFF0000u;  v0.y = t.f;
        t.u = u.y << 16;          v0.z = t.f;
        t.u = u.y & 0xFFFF0000u;  v0.w = t.f;
        t.u = u.z << 16;          v1.x = t.f;
        t.u = u.z & 0xFFFF0000u;  v1.y = t.f;
        t.u = u.w << 16;          v1.z = t.f;
        t.u = u.w & 0xFFFF0000u;  v1.w = t.f;

        v0.x = fmaxf(v0.x * SC0.x + SH0.x, 0.f);
        v0.y = fmaxf(v0.y * SC0.y + SH0.y, 0.f);
        v0.z = fmaxf(v0.z * SC0.z + SH0.z, 0.f);
        v0.w = fmaxf(v0.w * SC0.w + SH0.w, 0.f);
        v1.x = fmaxf(v1.x * SC1.x + SH1.x, 0.f);
        v1.y = fmaxf(v1.y * SC1.y + SH1.y, 0.f);
        v1.z = fmaxf(v1.z * SC1.z + SH1.z, 0.f);
        v1.w = fmaxf(v1.w * SC1.w + SH1.w, 0.f);

        o4[(long)c * 2]     = v0;
        o4[(long)c * 2 + 1] = v1;
    }
}

// ---------------------------------------------------------------------------
extern "C" void kernel_launch(void* const* d_in, const int* in_sizes, int n_in,
                              void* d_out, int out_size, void* d_ws, size_t ws_size,
                              hipStream_t stream) {
    const float* feat   = (const float*)d_in[0];
    const float* weight = (const float*)d_in[1];
    const float* gamma  = (const float*)d_in[2];
    const float* beta   = (const float*)d_in[3];
    const int*   nbr    = (const int*)d_in[4];
    float* out = (float*)d_out;

    char*  ws     = (char*)d_ws;
    float* gstats = (float*)(ws + WS_GSTATS);

    k_prep<<<PREPBLK, NTHR, 0, stream>>>(feat, weight, ws);
    k_conv<<<NBLK1, NTHR, 0, stream>>>(ws, nbr, gstats);
    k_norm<<<NBLK2, NTHR, 0, stream>>>(ws, out, gstats, gamma, beta);
}